// Round 3
// baseline (387.220 us; speedup 1.0000x reference)
//
#include <hip/hip_runtime.h>
#include <hip/hip_bf16.h>
#include <math.h>

#define B_ 32
#define E_ 16384
#define N_ 1000
#define D_ 128
#define NN_ (N_ * N_)
#define NTILE 4096   // (B_*E_)/128 edge-tiles of 128 edges
#define PBLK 512     // persistent blocks: 2 per CU

typedef __attribute__((ext_vector_type(8))) short bf16x8;
typedef __attribute__((ext_vector_type(4))) float f32x4;

// fp32 -> bf16 RNE (scalar; finite inputs)
__device__ __forceinline__ unsigned short f2bf(float f) {
    unsigned u = __float_as_uint(f);
    u += 0x7FFFu + ((u >> 16) & 1u);
    return (unsigned short)(u >> 16);
}

// packed pair fp32 -> bf16x2 (compiler emits v_cvt_pk_bf16_f32)
__device__ __forceinline__ unsigned pk2(float lo, float hi) {
    __hip_bfloat162 h = __float22bfloat162_rn(make_float2(lo, hi));
    return *(unsigned*)&h;
}

__device__ __forceinline__ f32x4 mfma16(bf16x8 a, bf16x8 b, f32x4 c) {
    return __builtin_amdgcn_mfma_f32_16x16x32_bf16(a, b, c, 0, 0, 0);
}

__device__ __forceinline__ float silu_(float z) {
    return z * __builtin_amdgcn_rcpf(1.0f + __expf(-z));
}

// decode packed cell: 0 = empty, else low 18 bits = quantized val+1 over [0,10]
__device__ __forceinline__ float decq(unsigned x) {
    return x ? (float)((x & 0x3FFFFu) - 1u) * (10.0f / 262142.0f) : 0.0f;
}

// async global->LDS, 16B per lane (dest = wave-uniform base + lane*16)
__device__ __forceinline__ void gload_lds16(const void* g, void* l) {
    __builtin_amdgcn_global_load_lds(
        (const __attribute__((address_space(1))) unsigned*)g,
        (__attribute__((address_space(3))) unsigned*)l, 16, 0, 0);
}

// Pre-swizzle W1,W2 (128x128 fp32) -> bf16 at byte row*256 + ((col*2)^((row&7)<<4))
// so LINEAR global_load_lds reproduces the swizzled LDS image (rule 21).
__global__ void prep_weights(const float* __restrict__ W1,
                             const float* __restrict__ W2,
                             unsigned short* __restrict__ wsz) {
    int t = blockIdx.x * 256 + threadIdx.x;   // 0..32767
    int w = t >> 14, e = t & 16383;
    int row = e >> 7, col = e & 127;
    float v = (w ? W2 : W1)[e];
    char* dst = (char*)wsz + (size_t)w * 32768 + row * 256 + ((col * 2) ^ ((row & 7) << 4));
    *(unsigned short*)dst = f2bf(v);
}

__global__ __launch_bounds__(256, 2) void mlp_scatter_kernel(
    const float* __restrict__ X, const int* __restrict__ EI,
    const unsigned short* __restrict__ wsz,
    const float* __restrict__ b1, const float* __restrict__ b2,
    const float* __restrict__ Wo, const float* __restrict__ bo,
    unsigned* __restrict__ out)
{
    __shared__ __align__(16) char Wb[65536];  // W1 | W2, bf16 swizzled
    __shared__ __align__(16) char Hs[16384];  // 4 waves x [32 edges][64 f] bf16

    const int tid = threadIdx.x;
    const int lane = tid & 63;
    const int wv = tid >> 6;
    const int l15 = lane & 15;
    const int g = lane >> 4;
    char* hw = Hs + wv * 4096;   // wave-private H half-tile

    const float bo0 = bo[0];

    // X fragments for one tile: B-operand layout, lane = edge l15, k contiguous
    float4 af[2][4][2];
    auto issue_af = [&](int t) {
        #pragma unroll
        for (int m = 0; m < 2; ++m) {
            const float* p0 = X + ((size_t)t * 128 + wv * 32 + m * 16 + l15) * D_;
            #pragma unroll
            for (int ks = 0; ks < 4; ++ks) {
                af[m][ks][0] = *(const float4*)(p0 + ks * 32 + g * 8);
                af[m][ks][1] = *(const float4*)(p0 + ks * 32 + g * 8 + 4);
            }
        }
    };

    issue_af(blockIdx.x);

    // stage both weight matrices once per block: 64KB linear, zero VALU
    #pragma unroll
    for (int it = 0; it < 16; ++it) {
        int off = it * 4096 + tid * 16;
        gload_lds16((const char*)wsz + off, Wb + off);
    }
    __syncthreads();   // the only barrier; tile loop is barrier-free

    for (int t = blockIdx.x; t < NTILE; t += PBLK) {
        // convert current X tile to bf16 fragments
        bf16x8 a[2][4];
        #pragma unroll
        for (int m = 0; m < 2; ++m)
            #pragma unroll
            for (int ks = 0; ks < 4; ++ks) {
                bf16x8 tt;
                unsigned* tu = (unsigned*)&tt;
                tu[0] = pk2(af[m][ks][0].x, af[m][ks][0].y);
                tu[1] = pk2(af[m][ks][0].z, af[m][ks][0].w);
                tu[2] = pk2(af[m][ks][1].x, af[m][ks][1].y);
                tu[3] = pk2(af[m][ks][1].z, af[m][ks][1].w);
                a[m][ks] = tt;
            }

        // prefetch next tile's X: in flight across this tile's compute
        if (t + PBLK < NTILE) issue_af(t + PBLK);

        f32x4 acc2[2][8];
        #pragma unroll
        for (int m = 0; m < 2; ++m)
            #pragma unroll
            for (int n = 0; n < 8; ++n)
                acc2[m][n] = (f32x4){0.f, 0.f, 0.f, 0.f};

        #pragma unroll
        for (int half = 0; half < 2; ++half) {
            // ---- GEMM1 (swapped): D1 = W1 . X^T, f1-rows half*64..+63 ----
            f32x4 acc1[2][4];
            #pragma unroll
            for (int m = 0; m < 2; ++m)
                #pragma unroll
                for (int nn = 0; nn < 4; ++nn)
                    acc1[m][nn] = (f32x4){0.f, 0.f, 0.f, 0.f};

            #pragma unroll
            for (int ks = 0; ks < 4; ++ks)
                #pragma unroll
                for (int nn = 0; nn < 4; ++nn) {
                    int row = l15 + (half * 4 + nn) * 16;
                    bf16x8 aw = *(const bf16x8*)(Wb + row * 256 +
                                  ((ks * 64 + g * 16) ^ ((row & 7) << 4)));
                    acc1[0][nn] = mfma16(aw, a[0][ks], acc1[0][nn]);
                    acc1[1][nn] = mfma16(aw, a[1][ks], acc1[1][nn]);
                }

            // ---- bias+silu -> H: lane holds 4 CONTIGUOUS features per edge ----
            // C layout: col = edge = l15, row = f1_local = nn*16 + g*4 + r
            #pragma unroll
            for (int nn = 0; nn < 4; ++nn) {
                float4 b1q = *(const float4*)(b1 + (half * 4 + nn) * 16 + g * 4);
                #pragma unroll
                for (int m = 0; m < 2; ++m) {
                    float h0 = silu_(acc1[m][nn][0] + b1q.x);
                    float h1 = silu_(acc1[m][nn][1] + b1q.y);
                    float h2 = silu_(acc1[m][nn][2] + b1q.z);
                    float h3 = silu_(acc1[m][nn][3] + b1q.w);
                    int edge = m * 16 + l15;
                    int fb = nn * 32 + g * 8;   // byte offset in 128B row
                    *(uint2*)(hw + edge * 128 + (fb ^ ((edge & 7) << 4))) =
                        make_uint2(pk2(h0, h1), pk2(h2, h3));
                }
            }

            // ---- GEMM2 partial (swapped): D2 = W2 . h1^T, k = half*64..+63 ----
            #pragma unroll
            for (int p2 = 0; p2 < 2; ++p2) {
                bf16x8 hb[2];
                #pragma unroll
                for (int m = 0; m < 2; ++m) {
                    int edge = m * 16 + l15;
                    hb[m] = *(const bf16x8*)(hw + edge * 128 +
                              ((p2 * 64 + g * 16) ^ ((edge & 7) << 4)));
                }
                #pragma unroll
                for (int n = 0; n < 8; ++n) {
                    int row = l15 + n * 16;
                    bf16x8 w2 = *(const bf16x8*)(Wb + 32768 + row * 256 +
                                  (((half * 2 + p2) * 64 + g * 16) ^ ((row & 7) << 4)));
                    acc2[0][n] = mfma16(w2, hb[0], acc2[0][n]);
                    acc2[1][n] = mfma16(w2, hb[1], acc2[1][n]);
                }
            }
        }

        // ---- epilogue: lane holds f2 = n*16+g*4+r for a FIXED edge (m,l15) ----
        float zed[2] = {0.f, 0.f};
        #pragma unroll
        for (int n = 0; n < 8; ++n) {
            float4 b2q = *(const float4*)(b2 + n * 16 + g * 4);
            float4 woq = *(const float4*)(Wo + n * 16 + g * 4);
            #pragma unroll
            for (int m = 0; m < 2; ++m) {
                zed[m] += silu_(acc2[m][n][0] + b2q.x) * woq.x;
                zed[m] += silu_(acc2[m][n][1] + b2q.y) * woq.y;
                zed[m] += silu_(acc2[m][n][2] + b2q.z) * woq.z;
                zed[m] += silu_(acc2[m][n][3] + b2q.w) * woq.w;
            }
        }
        #pragma unroll
        for (int m = 0; m < 2; ++m) {
            zed[m] += __shfl_xor(zed[m], 16, 64);
            zed[m] += __shfl_xor(zed[m], 32, 64);
        }

        // ---- sigmoid*10, pack (e<<18 | q), atomicMax scatter (last-e-wins) ----
        if (g == 0) {
            const int bb = t >> 7;
            const int e0 = (t & 127) * 128;
            #pragma unroll
            for (int m = 0; m < 2; ++m) {
                int eb = e0 + wv * 32 + m * 16 + l15;
                int s = EI[(size_t)bb * 2 * E_ + eb];
                int d = EI[(size_t)bb * 2 * E_ + E_ + eb];
                float z = zed[m] + bo0;
                float val = 10.0f * __builtin_amdgcn_rcpf(1.0f + __expf(-z));
                unsigned q = (unsigned)(val * 26214.2f + 0.5f) + 1u;  // 262142/10
                if (q > 0x3FFFFu) q = 0x3FFFFu;
                atomicMax(out + ((size_t)bb * NN_ + (size_t)s * N_ + d),
                          ((unsigned)eb << 18) | q);
            }
        }
    }
}

// Sparse finalize: only edge-touched cells are nonzero (~0.5M of 32M).
// S1: per edge, read both packed cells, compute final value -> ws.
// S2: write the final float to BOTH (s,d) and (d,s); all writers of a cell
// compute the identical value, so write races are benign.
__global__ __launch_bounds__(256) void finalize1(
    const int* __restrict__ EI, const unsigned* __restrict__ out,
    float* __restrict__ ev)
{
    int i = blockIdx.x * 256 + threadIdx.x;   // 0..B*E-1
    int b = i >> 14, e = i & 16383;
    int s = EI[(size_t)b * 2 * E_ + e];
    int d = EI[(size_t)b * 2 * E_ + E_ + e];
    const unsigned* ob = out + (size_t)b * NN_;
    ev[i] = 0.5f * (decq(ob[(size_t)s * N_ + d]) + decq(ob[(size_t)d * N_ + s]));
}

__global__ __launch_bounds__(256) void finalize2(
    const int* __restrict__ EI, const float* __restrict__ ev,
    float* __restrict__ outf)
{
    int i = blockIdx.x * 256 + threadIdx.x;
    int b = i >> 14, e = i & 16383;
    int s = EI[(size_t)b * 2 * E_ + e];
    int d = EI[(size_t)b * 2 * E_ + E_ + e];
    float v = ev[i];
    float* ob = outf + (size_t)b * NN_;
    ob[(size_t)s * N_ + d] = v;
    ob[(size_t)d * N_ + s] = v;
}

// Dense fallback (used only if ws too small for the edge-value buffer).
__global__ __launch_bounds__(256) void symmetrize_kernel(unsigned* __restrict__ out) {
    const int b = blockIdx.y;
    const int ti = blockIdx.x >> 5;
    const int tj = blockIdx.x & 31;
    if (ti > tj) return;
    __shared__ unsigned ta[32][33];
    __shared__ unsigned tb[32][33];
    const int j = threadIdx.x & 31;
    const int i0 = threadIdx.x >> 5;
    unsigned* ob = out + (size_t)b * NN_;
    float* of = (float*)ob;
    #pragma unroll
    for (int rr = 0; rr < 4; ++rr) {
        int i = rr * 8 + i0;
        int gi = ti * 32 + i, gj = tj * 32 + j;
        ta[i][j] = (gi < N_ && gj < N_) ? ob[(size_t)gi * N_ + gj] : 0u;
        int hi = tj * 32 + i, hj = ti * 32 + j;
        tb[i][j] = (hi < N_ && hj < N_) ? ob[(size_t)hi * N_ + hj] : 0u;
    }
    __syncthreads();
    #pragma unroll
    for (int rr = 0; rr < 4; ++rr) {
        int i = rr * 8 + i0;
        int gi = ti * 32 + i, gj = tj * 32 + j;
        if (gi < N_ && gj < N_)
            of[(size_t)gi * N_ + gj] = 0.5f * (decq(ta[i][j]) + decq(tb[j][i]));
        int hi = tj * 32 + i, hj = ti * 32 + j;
        if (hi < N_ && hj < N_)
            of[(size_t)hi * N_ + hj] = 0.5f * (decq(tb[i][j]) + decq(ta[j][i]));
    }
}

extern "C" void kernel_launch(void* const* d_in, const int* in_sizes, int n_in,
                              void* d_out, int out_size, void* d_ws, size_t ws_size,
                              hipStream_t stream) {
    const float* X  = (const float*)d_in[0];
    const int*   EI = (const int*)d_in[1];
    const float* W1 = (const float*)d_in[2];
    const float* b1 = (const float*)d_in[3];
    const float* W2 = (const float*)d_in[4];
    const float* b2 = (const float*)d_in[5];
    const float* Wo = (const float*)d_in[6];
    const float* bo = (const float*)d_in[7];
    unsigned* out = (unsigned*)d_out;
    unsigned short* wsz = (unsigned short*)d_ws;
    float* ev = (float*)((char*)d_ws + 65536);

    prep_weights<<<dim3(128), dim3(256), 0, stream>>>(W1, W2, wsz);
    hipMemsetAsync(d_out, 0, (size_t)B_ * NN_ * sizeof(float), stream);
    mlp_scatter_kernel<<<dim3(PBLK), dim3(256), 0, stream>>>(
        X, EI, wsz, b1, b2, Wo, bo, out);

    if (ws_size >= 65536 + (size_t)B_ * E_ * sizeof(float)) {
        finalize1<<<dim3((B_ * E_) / 256), dim3(256), 0, stream>>>(EI, out, ev);
        finalize2<<<dim3((B_ * E_) / 256), dim3(256), 0, stream>>>(EI, ev, (float*)d_out);
    } else {
        symmetrize_kernel<<<dim3(32 * 32, B_), dim3(256), 0, stream>>>(out);
    }
}

// Round 5
// 144.285 us; speedup vs baseline: 2.6837x; 2.6837x over previous
//
#include <hip/hip_runtime.h>
#include <hip/hip_bf16.h>
#include <math.h>

#define B_ 32
#define E_ 16384
#define N_ 1000
#define D_ 128
#define NN_ (N_ * N_)
#define T_ 4   // 128-edge sub-tiles per block; grid = B_*E_/(128*T_) = 1024

typedef __attribute__((ext_vector_type(8))) short bf16x8;
typedef __attribute__((ext_vector_type(4))) float f32x4;

// fp32 -> bf16 RNE (scalar; finite inputs)
__device__ __forceinline__ unsigned short f2bf(float f) {
    unsigned u = __float_as_uint(f);
    u += 0x7FFFu + ((u >> 16) & 1u);
    return (unsigned short)(u >> 16);
}

// packed pair fp32 -> bf16x2 (v_cvt_pk_bf16_f32)
__device__ __forceinline__ unsigned pk2(float lo, float hi) {
    __hip_bfloat162 h = __float22bfloat162_rn(make_float2(lo, hi));
    return *(unsigned*)&h;
}

__device__ __forceinline__ f32x4 mfma16(bf16x8 a, bf16x8 b, f32x4 c) {
    return __builtin_amdgcn_mfma_f32_16x16x32_bf16(a, b, c, 0, 0, 0);
}

__device__ __forceinline__ float silu_(float z) {
    return z * __builtin_amdgcn_rcpf(1.0f + __expf(-z));
}

// decode packed cell: 0 = empty, else low 18 bits = quantized val+1 over [0,10]
__device__ __forceinline__ float decq(unsigned x) {
    return x ? (float)((x & 0x3FFFFu) - 1u) * (10.0f / 262142.0f) : 0.0f;
}

// async global->LDS, 16B per lane (dest = wave-uniform base + lane*16)
__device__ __forceinline__ void gload_lds16(const void* g, void* l) {
    __builtin_amdgcn_global_load_lds(
        (const __attribute__((address_space(1))) unsigned*)g,
        (__attribute__((address_space(3))) unsigned*)l, 16, 0, 0);
}

// Pre-swizzle W1,W2 (128x128 fp32) -> bf16 at byte row*256 + ((col*2)^((row&7)<<4))
// so LINEAR global_load_lds reproduces the swizzled LDS image (rule 21).
__global__ void prep_weights(const float* __restrict__ W1,
                             const float* __restrict__ W2,
                             unsigned short* __restrict__ wsz) {
    int t = blockIdx.x * 256 + threadIdx.x;   // 0..32767
    int w = t >> 14, e = t & 16383;
    int row = e >> 7, col = e & 127;
    float v = (w ? W2 : W1)[e];
    char* dst = (char*)wsz + (size_t)w * 32768 + row * 256 + ((col * 2) ^ ((row & 7) << 4));
    *(unsigned short*)dst = f2bf(v);
}

__global__ __launch_bounds__(256, 2) void mlp_scatter_kernel(
    const float* __restrict__ X, const int* __restrict__ EI,
    const unsigned short* __restrict__ wsz,
    const float* __restrict__ b1, const float* __restrict__ b2,
    const float* __restrict__ Wo, const float* __restrict__ bo,
    unsigned* __restrict__ out)
{
    __shared__ __align__(16) char Wb[65536];   // W1 | W2 bf16, swizzled
    __shared__ __align__(16) char Hs[8192];    // 4 waves x [32 edges][32 f] bf16
    __shared__ __align__(16) float BiasL[384]; // b1 | b2 | Wo (fp32)

    const int tid = threadIdx.x;
    const int lane = tid & 63;
    const int wv = tid >> 6;
    const int l15 = lane & 15;
    const int g = (lane >> 4) & 3;
    char* hw = (char*)Hs + wv * 2048;

    const int bb = blockIdx.x >> 5;                 // batch (32 blocks per batch)
    const int e0 = (blockIdx.x & 31) * (128 * T_);  // edge base within batch

    // stage biases to LDS (keeps the main loop free of compiler vmem ops)
    if (tid < 96) {
        const float* src = tid < 32 ? b1 : (tid < 64 ? b2 : Wo);
        ((f32x4*)BiasL)[tid] = ((const f32x4*)src)[tid & 31];
    }
    const float bo0 = bo[0];

    // EI preload for all sub-tiles (prologue only; static indexing -> registers)
    int eis[T_][2], eid[T_][2];
    #pragma unroll
    for (int st = 0; st < T_; ++st)
        #pragma unroll
        for (int m = 0; m < 2; ++m) {
            int e = e0 + st * 128 + wv * 32 + m * 16 + l15;
            eis[st][m] = EI[(size_t)bb * 2 * E_ + e];
            eid[st][m] = EI[(size_t)bb * 2 * E_ + E_ + e];
        }

    // X prefetch registers: asm-pinned (not rematerializable). EARLY-CLOBBER
    // outputs ("=&v") so no output tuple can alias the address pair %8.
    f32x4 af[2][4][2];

#define ISSUE_M(stv, mm) do {                                                        \
        unsigned long long _ad = (unsigned long long)X +                             \
            (((unsigned long long)((size_t)bb * E_ + e0 + (stv) * 128 + wv * 32 +    \
                                   (mm) * 16 + l15)) << 9) + (unsigned)(g * 32);     \
        asm volatile(                                                                \
            "global_load_dwordx4 %0, %8, off\n\t"                                    \
            "global_load_dwordx4 %1, %8, off offset:16\n\t"                          \
            "global_load_dwordx4 %2, %8, off offset:128\n\t"                         \
            "global_load_dwordx4 %3, %8, off offset:144\n\t"                         \
            "global_load_dwordx4 %4, %8, off offset:256\n\t"                         \
            "global_load_dwordx4 %5, %8, off offset:272\n\t"                         \
            "global_load_dwordx4 %6, %8, off offset:384\n\t"                         \
            "global_load_dwordx4 %7, %8, off offset:400"                             \
            : "=&v"(af[mm][0][0]), "=&v"(af[mm][0][1]), "=&v"(af[mm][1][0]),         \
              "=&v"(af[mm][1][1]), "=&v"(af[mm][2][0]), "=&v"(af[mm][2][1]),         \
              "=&v"(af[mm][3][0]), "=&v"(af[mm][3][1])                               \
            : "v"(_ad));                                                             \
    } while (0)

    ISSUE_M(0, 0);
    ISSUE_M(0, 1);

    // stage both weight matrices: 64KB linear, zero VALU
    #pragma unroll
    for (int it = 0; it < 16; ++it) {
        int off = it * 4096 + tid * 16;
        gload_lds16((const char*)wsz + off, Wb + off);
    }
    asm volatile("s_waitcnt vmcnt(0)" ::: "memory");
    __builtin_amdgcn_sched_barrier(0);
    __syncthreads();   // the only barrier

    #pragma unroll
    for (int st = 0; st < T_; ++st) {
        // all but the newest 2 vmem ops (= prev sub-tile's atomics) complete,
        // i.e. this sub-tile's 16 X loads have landed.
        asm volatile("s_waitcnt vmcnt(2)" ::: "memory");
        __builtin_amdgcn_sched_barrier(0);

        // convert X tile to bf16 fragments (af regs die here)
        bf16x8 a[2][4];
        #pragma unroll
        for (int m = 0; m < 2; ++m)
            #pragma unroll
            for (int ks = 0; ks < 4; ++ks) {
                bf16x8 t;
                unsigned* tu = (unsigned*)&t;
                tu[0] = pk2(af[m][ks][0][0], af[m][ks][0][1]);
                tu[1] = pk2(af[m][ks][0][2], af[m][ks][0][3]);
                tu[2] = pk2(af[m][ks][1][0], af[m][ks][1][1]);
                tu[3] = pk2(af[m][ks][1][2], af[m][ks][1][3]);
                a[m][ks] = t;
            }

        f32x4 acc2[2][8];
        #pragma unroll
        for (int m = 0; m < 2; ++m)
            #pragma unroll
            for (int n = 0; n < 8; ++n)
                acc2[m][n] = (f32x4){0.f, 0.f, 0.f, 0.f};

        // quarter-feature pipeline: GEMM1 q -> H -> GEMM2 k-slice q
        #pragma unroll
        for (int q = 0; q < 4; ++q) {
            f32x4 acc1[2][2];
            #pragma unroll
            for (int m = 0; m < 2; ++m)
                #pragma unroll
                for (int nn = 0; nn < 2; ++nn)
                    acc1[m][nn] = (f32x4){0.f, 0.f, 0.f, 0.f};

            #pragma unroll
            for (int ks = 0; ks < 4; ++ks)
                #pragma unroll
                for (int nn = 0; nn < 2; ++nn) {
                    int row = l15 + (q * 2 + nn) * 16;
                    bf16x8 aw = *(const bf16x8*)(Wb + row * 256 +
                                  ((ks * 64 + g * 16) ^ ((row & 7) << 4)));
                    acc1[0][nn] = mfma16(aw, a[0][ks], acc1[0][nn]);
                    acc1[1][nn] = mfma16(aw, a[1][ks], acc1[1][nn]);
                }

            #pragma unroll
            for (int nn = 0; nn < 2; ++nn) {
                f32x4 b1q = ((f32x4*)BiasL)[(q * 2 + nn) * 4 + g];
                #pragma unroll
                for (int m = 0; m < 2; ++m) {
                    float h0 = silu_(acc1[m][nn][0] + b1q[0]);
                    float h1 = silu_(acc1[m][nn][1] + b1q[1]);
                    float h2 = silu_(acc1[m][nn][2] + b1q[2]);
                    float h3 = silu_(acc1[m][nn][3] + b1q[3]);
                    int edge = m * 16 + l15;
                    *(uint2*)(hw + edge * 64 + ((nn * 32 + g * 8) ^ ((edge & 6) << 3))) =
                        make_uint2(pk2(h0, h1), pk2(h2, h3));
                }
            }

            // prefetch chunk m=0 for next sub-tile where acc1/a pressure is low
            if (st + 1 < T_ && q == 2) ISSUE_M(st + 1, 0);

            bf16x8 hb[2];
            #pragma unroll
            for (int m = 0; m < 2; ++m) {
                int edge = m * 16 + l15;
                hb[m] = *(const bf16x8*)(hw + edge * 64 + ((g * 16) ^ ((edge & 6) << 3)));
            }
            #pragma unroll
            for (int n = 0; n < 8; ++n) {
                int row = l15 + n * 16;
                bf16x8 w2 = *(const bf16x8*)(Wb + 32768 + row * 256 +
                              ((q * 64 + g * 16) ^ ((row & 7) << 4)));
                acc2[0][n] = mfma16(w2, hb[0], acc2[0][n]);
                acc2[1][n] = mfma16(w2, hb[1], acc2[1][n]);
            }
        }

        // epilogue: lane holds f2 = n*16+g*4+r for edge m*16+l15
        float zed[2] = {0.f, 0.f};
        #pragma unroll
        for (int n = 0; n < 8; ++n) {
            f32x4 b2q = ((f32x4*)BiasL)[32 + n * 4 + g];
            f32x4 woq = ((f32x4*)BiasL)[64 + n * 4 + g];
            #pragma unroll
            for (int m = 0; m < 2; ++m) {
                zed[m] += silu_(acc2[m][n][0] + b2q[0]) * woq[0];
                zed[m] += silu_(acc2[m][n][1] + b2q[1]) * woq[1];
                zed[m] += silu_(acc2[m][n][2] + b2q[2]) * woq[2];
                zed[m] += silu_(acc2[m][n][3] + b2q[3]) * woq[3];
            }
        }

        // prefetch chunk m=1 (before atomics so vmcnt(2) ordering holds)
        if (st + 1 < T_) ISSUE_M(st + 1, 1);

        #pragma unroll
        for (int m = 0; m < 2; ++m) {
            zed[m] += __shfl_xor(zed[m], 16, 64);
            zed[m] += __shfl_xor(zed[m], 32, 64);
        }

        // sigmoid*10, pack (e<<18 | q), atomicMax scatter (last-e-wins)
        if (g == 0) {
            #pragma unroll
            for (int m = 0; m < 2; ++m) {
                int e = e0 + st * 128 + wv * 32 + m * 16 + l15;
                float z = zed[m] + bo0;
                float val = 10.0f * __builtin_amdgcn_rcpf(1.0f + __expf(-z));
                unsigned qv = (unsigned)(val * 26214.2f + 0.5f) + 1u;  // 262142/10
                if (qv > 0x3FFFFu) qv = 0x3FFFFu;
                unsigned packed = ((unsigned)e << 18) | qv;
                unsigned long long aaddr = (unsigned long long)(out +
                    ((size_t)bb * NN_ + (size_t)eis[st][m] * N_ + eid[st][m]));
                asm volatile("global_atomic_umax %0, %1, off"
                             :: "v"(aaddr), "v"(packed) : "memory");
            }
        }
    }
#undef ISSUE_M
}

// Sparse finalize: only edge-touched cells are nonzero (~0.5M of 32M).
__global__ __launch_bounds__(256) void finalize1(
    const int* __restrict__ EI, const unsigned* __restrict__ out,
    float* __restrict__ ev)
{
    int i = blockIdx.x * 256 + threadIdx.x;   // 0..B*E-1
    int b = i >> 14, e = i & 16383;
    int s = EI[(size_t)b * 2 * E_ + e];
    int d = EI[(size_t)b * 2 * E_ + E_ + e];
    const unsigned* ob = out + (size_t)b * NN_;
    ev[i] = 0.5f * (decq(ob[(size_t)s * N_ + d]) + decq(ob[(size_t)d * N_ + s]));
}

__global__ __launch_bounds__(256) void finalize2(
    const int* __restrict__ EI, const float* __restrict__ ev,
    float* __restrict__ outf)
{
    int i = blockIdx.x * 256 + threadIdx.x;
    int b = i >> 14, e = i & 16383;
    int s = EI[(size_t)b * 2 * E_ + e];
    int d = EI[(size_t)b * 2 * E_ + E_ + e];
    float v = ev[i];
    float* ob = outf + (size_t)b * NN_;
    ob[(size_t)s * N_ + d] = v;
    ob[(size_t)d * N_ + s] = v;
}

// Dense fallback (only if ws too small).
__global__ __launch_bounds__(256) void symmetrize_kernel(unsigned* __restrict__ out) {
    const int b = blockIdx.y;
    const int ti = blockIdx.x >> 5;
    const int tj = blockIdx.x & 31;
    if (ti > tj) return;
    __shared__ unsigned ta[32][33];
    __shared__ unsigned tb[32][33];
    const int j = threadIdx.x & 31;
    const int i0 = threadIdx.x >> 5;
    unsigned* ob = out + (size_t)b * NN_;
    float* of = (float*)ob;
    #pragma unroll
    for (int rr = 0; rr < 4; ++rr) {
        int i = rr * 8 + i0;
        int gi = ti * 32 + i, gj = tj * 32 + j;
        ta[i][j] = (gi < N_ && gj < N_) ? ob[(size_t)gi * N_ + gj] : 0u;
        int hi = tj * 32 + i, hj = ti * 32 + j;
        tb[i][j] = (hi < N_ && hj < N_) ? ob[(size_t)hi * N_ + hj] : 0u;
    }
    __syncthreads();
    #pragma unroll
    for (int rr = 0; rr < 4; ++rr) {
        int i = rr * 8 + i0;
        int gi = ti * 32 + i, gj = tj * 32 + j;
        if (gi < N_ && gj < N_)
            of[(size_t)gi * N_ + gj] = 0.5f * (decq(ta[i][j]) + decq(tb[j][i]));
        int hi = tj * 32 + i, hj = ti * 32 + j;
        if (hi < N_ && hj < N_)
            of[(size_t)hi * N_ + hj] = 0.5f * (decq(tb[i][j]) + decq(ta[j][i]));
    }
}

extern "C" void kernel_launch(void* const* d_in, const int* in_sizes, int n_in,
                              void* d_out, int out_size, void* d_ws, size_t ws_size,
                              hipStream_t stream) {
    const float* X  = (const float*)d_in[0];
    const int*   EI = (const int*)d_in[1];
    const float* W1 = (const float*)d_in[2];
    const float* b1 = (const float*)d_in[3];
    const float* W2 = (const float*)d_in[4];
    const float* b2 = (const float*)d_in[5];
    const float* Wo = (const float*)d_in[6];
    const float* bo = (const float*)d_in[7];
    unsigned* out = (unsigned*)d_out;
    unsigned short* wsz = (unsigned short*)d_ws;
    float* ev = (float*)((char*)d_ws + 65536);

    prep_weights<<<dim3(128), dim3(256), 0, stream>>>(W1, W2, wsz);
    hipMemsetAsync(d_out, 0, (size_t)B_ * NN_ * sizeof(float), stream);
    mlp_scatter_kernel<<<dim3((B_ * E_) / (128 * T_)), dim3(256), 0, stream>>>(
        X, EI, wsz, b1, b2, Wo, bo, out);

    if (ws_size >= 65536 + (size_t)B_ * E_ * sizeof(float)) {
        finalize1<<<dim3((B_ * E_) / 256), dim3(256), 0, stream>>>(EI, out, ev);
        finalize2<<<dim3((B_ * E_) / 256), dim3(256), 0, stream>>>(EI, ev, (float*)d_out);
    } else {
        symmetrize_kernel<<<dim3(32 * 32, B_), dim3(256), 0, stream>>>(out);
    }
}